// Round 2
// baseline (208.587 us; speedup 1.0000x reference)
//
#include <hip/hip_runtime.h>
#include <hip/hip_bf16.h>
#include <stdint.h>

#define BATCH 8192
#define PEP 15
#define INC 512
#define OUTC 512
#define XROW (PEP*INC)          // 7680 floats per batch row
#define BM 64
#define BK 32
#define NSTEPS (INC/BK)         // 16
#define WT_P_ELEMS (INC*OUTC)   // 262144 elems per p

typedef float f32x4 __attribute__((ext_vector_type(4)));
typedef short s16x8 __attribute__((ext_vector_type(8)));

__device__ __forceinline__ ushort f2b(float v) {
  // round-to-nearest-even fp32 -> bf16
  uint u = __float_as_uint(v);
  u += 0x7fffu + ((u >> 16) & 1u);
  return (ushort)(u >> 16);
}

// ---------------- kernel 1: W [p][k][n] fp32 -> fragment-linear bf16 ----------------
// wt[(((p*16+ks)*32+n16)*64+l)*8+e] = bf16(w[p][ks*32+(l>>4)*8+e][n16*16+(l&15)])
// so that per (ks, n16-group) the 64 lanes' 16B fragments are contiguous (1 KB).
__global__ __launch_bounds__(256) void wt_kernel(const float* __restrict__ w,
                                                 ushort* __restrict__ wt) {
  int gid = blockIdx.x * 256 + threadIdx.x;   // 15*16*32*64 = 491520 exactly
  int l   = gid & 63;
  int n16 = (gid >> 6) & 31;
  int ks  = (gid >> 11) & 15;
  int p   = gid >> 15;
  int fr = l & 15, g = l >> 4;
  const float* src = w + (size_t)p * WT_P_ELEMS + (size_t)(ks * 32 + g * 8) * OUTC + n16 * 16 + fr;
  s16x8 hv;
#pragma unroll
  for (int e = 0; e < 8; ++e) hv[e] = (short)f2b(src[(size_t)e * OUTC]);
  *(s16x8*)(wt + (size_t)gid * 8) = hv;
}

// ---------------- kernel 2: per-p GEMM, BM=64 x BN=512, 4 waves, pipelined ----------------
__global__ __launch_bounds__(256, 2) void gemm_kernel(const float* __restrict__ x,
                                                      const ushort* __restrict__ wt,
                                                      const float* __restrict__ bias,
                                                      float* __restrict__ out) {
  __shared__ ushort Bs[2][32 * 512];   // 2 x 32 KB, fragment-linear (group*1024B + lane*16B)
  __shared__ ushort As[2][BM][BK + 8]; // 2 x 5 KB, 80B row pitch (16B-aligned, 2-way = free)

  const int t    = threadIdx.x;
  const int lane = t & 63;
  const int wid  = t >> 6;            // wave owns n-cols [wid*128, +128)
  const int fr   = lane & 15;
  const int g    = lane >> 4;

  const int p  = blockIdx.z;
  const int m0 = blockIdx.x * BM;

  f32x4 acc[4][8] = {};

  // A staging: thread -> row ar, 8 floats at col ac
  const int ar = t >> 2;
  const int ac = (t & 3) * 8;
  const float* a_src = x + (size_t)(m0 + ar) * XROW + p * INC + ac;

  const ushort* wt_p = wt + (size_t)p * WT_P_ELEMS;

  // ---- prologue: A(0) regs first (so cvt waits vmcnt(8), not 0), then B(0) -> Bs[0]
  f32x4 pa[2][2];
  pa[0][0] = *(const f32x4*)(a_src);
  pa[0][1] = *(const f32x4*)(a_src + 4);
#pragma unroll
  for (int q = 0; q < 8; ++q) {
    __builtin_amdgcn_global_load_lds(
        (const __attribute__((address_space(1))) void*)(wt_p + (size_t)(wid * 8 + q) * 512 + lane * 8),
        (__attribute__((address_space(3))) void*)(&Bs[0][(wid * 8 + q) * 512]),
        16, 0, 0);
  }

#pragma unroll
  for (int ks = 0; ks < NSTEPS; ++ks) {
    const int cur = ks & 1;
    const int nxt = cur ^ 1;

    // cvt A(ks) fp32 -> bf16, one ds_write_b128
    {
      f32x4 v0 = pa[cur][0], v1 = pa[cur][1];
      s16x8 hv;
      hv[0] = (short)f2b(v0[0]); hv[1] = (short)f2b(v0[1]);
      hv[2] = (short)f2b(v0[2]); hv[3] = (short)f2b(v0[3]);
      hv[4] = (short)f2b(v1[0]); hv[5] = (short)f2b(v1[1]);
      hv[6] = (short)f2b(v1[2]); hv[7] = (short)f2b(v1[3]);
      *(s16x8*)&As[cur][ar][ac] = hv;
    }

    __syncthreads();  // drains vmcnt: B(ks) staged; As[cur] written (lgkm)

    // fragments: A 2-way (free), B conflict-free (lane-contiguous)
    s16x8 af[4], bfv[8];
#pragma unroll
    for (int mf = 0; mf < 4; ++mf)
      af[mf] = *(const s16x8*)&As[cur][mf * 16 + fr][g * 8];
#pragma unroll
    for (int nf = 0; nf < 8; ++nf)
      bfv[nf] = *(const s16x8*)&Bs[cur][(wid * 8 + nf) * 512 + lane * 8];

    if (ks + 1 < NSTEPS) {
      // prefetch A(ks+1) -> regs (flies through ds_reads + MFMA below)
      pa[nxt][0] = *(const f32x4*)(a_src + (ks + 1) * BK);
      pa[nxt][1] = *(const f32x4*)(a_src + (ks + 1) * BK + 4);
      // stage B(ks+1) -> Bs[nxt]; full-iteration flight window until next barrier
#pragma unroll
      for (int q = 0; q < 8; ++q) {
        __builtin_amdgcn_global_load_lds(
            (const __attribute__((address_space(1))) void*)(wt_p + (size_t)(ks + 1) * 16384 + (size_t)(wid * 8 + q) * 512 + lane * 8),
            (__attribute__((address_space(3))) void*)(&Bs[nxt][(wid * 8 + q) * 512]),
            16, 0, 0);
      }
    }

#pragma unroll
    for (int mf = 0; mf < 4; ++mf)
#pragma unroll
      for (int nf = 0; nf < 8; ++nf)
        acc[mf][nf] = __builtin_amdgcn_mfma_f32_16x16x32_bf16(af[mf], bfv[nf], acc[mf][nf], 0, 0, 0);
  }

  // epilogue: C/D layout col=lane&15, row=(lane>>4)*4+r (m89-verified)
  float bv[8];
#pragma unroll
  for (int nf = 0; nf < 8; ++nf) bv[nf] = bias[p * OUTC + wid * 128 + nf * 16 + fr];

  float* op = out + (size_t)(m0 + g * 4) * XROW + p * INC + wid * 128;
#pragma unroll
  for (int mf = 0; mf < 4; ++mf)
#pragma unroll
    for (int nf = 0; nf < 8; ++nf)
#pragma unroll
      for (int r = 0; r < 4; ++r)
        op[(size_t)(mf * 16 + r) * XROW + nf * 16 + fr] = acc[mf][nf][r] + bv[nf];
}

// ---------------- fallback (only if ws too small): naive fp32 ----------------
__global__ void naive_kernel(const float* __restrict__ x, const float* __restrict__ w,
                             const float* __restrict__ bias, float* __restrict__ out) {
  size_t i = (size_t)blockIdx.x * 256 + threadIdx.x;
  if (i >= (size_t)BATCH * PEP * OUTC) return;
  int o  = (int)(i & (OUTC - 1));
  int pp = (int)((i >> 9) % PEP);
  size_t b = i / ((size_t)PEP * OUTC);
  const float* xr = x + b * XROW + pp * INC;
  const float* wc = w + (size_t)pp * INC * OUTC + o;
  float s = bias[pp * OUTC + o];
  for (int k = 0; k < INC; ++k) s += xr[k] * wc[(size_t)k * OUTC];
  out[i] = s;
}

extern "C" void kernel_launch(void* const* d_in, const int* in_sizes, int n_in,
                              void* d_out, int out_size, void* d_ws, size_t ws_size,
                              hipStream_t stream) {
  const float* x    = (const float*)d_in[0];
  const float* w    = (const float*)d_in[1];
  const float* bias = (const float*)d_in[2];
  float* out = (float*)d_out;

  const size_t wt_bytes = (size_t)PEP * INC * OUTC * sizeof(ushort);  // 7.9 MB
  if (ws_size >= wt_bytes) {
    wt_kernel<<<1920, 256, 0, stream>>>(w, (ushort*)d_ws);
    dim3 grid(BATCH / BM, 1, PEP);
    gemm_kernel<<<grid, 256, 0, stream>>>(x, (const ushort*)d_ws, bias, out);
  } else {
    size_t total = (size_t)BATCH * PEP * OUTC;
    naive_kernel<<<(int)((total + 255) / 256), 256, 0, stream>>>(x, w, bias, out);
  }
}